// Round 4
// baseline (505.540 us; speedup 1.0000x reference)
//
#include <hip/hip_runtime.h>
#include <hip/hip_cooperative_groups.h>

namespace cg = cooperative_groups;

#define BN_EPS 1e-5f

typedef __attribute__((ext_vector_type(8))) short short8;
typedef __attribute__((ext_vector_type(8))) unsigned short ushort8v;
typedef __attribute__((ext_vector_type(4))) float floatx4;

#define GLL(gp, lp)                                                            \
    __builtin_amdgcn_global_load_lds(                                          \
        (const __attribute__((address_space(1))) void*)(gp),                   \
        (__attribute__((address_space(3))) void*)(lp), 16, 0, 0)

__device__ inline unsigned short f2bf(float f) {
    unsigned int u = __float_as_uint(f);
    unsigned int r = (u + 0x7FFF + ((u >> 16) & 1)) >> 16;  // RNE
    return (unsigned short)r;
}

__device__ inline float bf2f(unsigned short u) {
    return __uint_as_float(((unsigned int)u) << 16);
}

// ---------------- prep: count in-degree + fp32->bf16 casts (merged) --------

__global__ void prep_kernel(const int* __restrict__ col, int* __restrict__ cnt,
                            const float* __restrict__ x, const float* __restrict__ W1,
                            const float* __restrict__ W2, ushort* __restrict__ xbf,
                            ushort* __restrict__ W1bf, ushort* __restrict__ W2bf,
                            int E, int n4x, int n4w) {
    int i = blockIdx.x * blockDim.x + threadIdx.x;
    if (i < E) {
        atomicAdd(&cnt[col[i]], 1);
        return;
    }
    int j = i - E;
    const float* src;
    ushort* dst;
    if (j < n4x) { src = x; dst = xbf; }
    else if (j < n4x + n4w) { src = W1; dst = W1bf; j -= n4x; }
    else if (j < n4x + 2 * n4w) { src = W2; dst = W2bf; j -= n4x + n4w; }
    else return;
    float4 v = ((const float4*)src)[j];
    ushort4 o;
    o.x = f2bf(v.x); o.y = f2bf(v.y); o.z = f2bf(v.z); o.w = f2bf(v.w);
    ((ushort4*)dst)[j] = o;
}

// single-block scan over N counts -> rowptr/cursor; also computes dis.
__global__ __launch_bounds__(1024) void scan_dis_kernel(
    const int* __restrict__ cnt, float* __restrict__ dis,
    int* __restrict__ rowptr, int* __restrict__ cursor, int N) {
    __shared__ int sums[1024];
    int t = threadIdx.x;
    int per = (N + 1023) / 1024;
    int start = t * per;
    int local = 0;
    for (int i = 0; i < per; i++) {
        int idx = start + i;
        if (idx < N) {
            int cv = cnt[idx];
            local += cv;
            dis[idx] = rsqrtf((float)(cv + 1));   // +1 self loop
        }
    }
    sums[t] = local;
    __syncthreads();
    for (int off = 1; off < 1024; off <<= 1) {
        int v = (t >= off) ? sums[t - off] : 0;
        __syncthreads();
        sums[t] += v;
        __syncthreads();
    }
    int run = (t == 0) ? 0 : sums[t - 1];
    for (int i = 0; i < per; i++) {
        int idx = start + i;
        if (idx < N) {
            rowptr[idx] = run;
            cursor[idx] = run;
            run += cnt[idx];
        }
    }
    if (t == 0) rowptr[N] = sums[1023];
}

// scatter: build CSR adjacency with pre-baked dis[row].
__global__ void scatter_kernel(const int* __restrict__ row, const int* __restrict__ col,
                               const float* __restrict__ dis,
                               int* __restrict__ cursor, int2* __restrict__ adjw, int E) {
    int e = blockIdx.x * blockDim.x + threadIdx.x;
    if (e < E) {
        int r = row[e];
        int pos = atomicAdd(&cursor[col[e]], 1);
        adjw[pos] = make_int2(r, __float_as_int(dis[r]));
    }
}

// ---------------- gather core: one WAVE per node, C=256 --------------------
// 64 lanes x ushort4 = 256 channels. 4-way edge unroll, named scalars only
// (rule #20: no runtime-indexed arrays). No LDS, no barriers.

__device__ inline float4 gather_node(const ushort4* __restrict__ x4,
                                     const int2* __restrict__ adjw,
                                     int e0, int e1, int lane, int v, float dv) {
    float p0 = 0.f, p1 = 0.f, p2 = 0.f, p3 = 0.f;
    float q0 = 0.f, q1 = 0.f, q2 = 0.f, q3 = 0.f;
    float r0 = 0.f, r1 = 0.f, r2 = 0.f, r3 = 0.f;
    float s0 = 0.f, s1 = 0.f, s2 = 0.f, s3 = 0.f;
    int e = e0;
    for (; e + 3 < e1; e += 4) {
        int2 ea = adjw[e];
        int2 eb = adjw[e + 1];
        int2 ec = adjw[e + 2];
        int2 ed = adjw[e + 3];
        float wa = __int_as_float(ea.y) * dv;
        float wb = __int_as_float(eb.y) * dv;
        float wc = __int_as_float(ec.y) * dv;
        float wd = __int_as_float(ed.y) * dv;
        ushort4 ua = x4[(size_t)ea.x * 64 + lane];
        ushort4 ub = x4[(size_t)eb.x * 64 + lane];
        ushort4 uc = x4[(size_t)ec.x * 64 + lane];
        ushort4 ud = x4[(size_t)ed.x * 64 + lane];
        p0 = fmaf(bf2f(ua.x), wa, p0); p1 = fmaf(bf2f(ua.y), wa, p1);
        p2 = fmaf(bf2f(ua.z), wa, p2); p3 = fmaf(bf2f(ua.w), wa, p3);
        q0 = fmaf(bf2f(ub.x), wb, q0); q1 = fmaf(bf2f(ub.y), wb, q1);
        q2 = fmaf(bf2f(ub.z), wb, q2); q3 = fmaf(bf2f(ub.w), wb, q3);
        r0 = fmaf(bf2f(uc.x), wc, r0); r1 = fmaf(bf2f(uc.y), wc, r1);
        r2 = fmaf(bf2f(uc.z), wc, r2); r3 = fmaf(bf2f(uc.w), wc, r3);
        s0 = fmaf(bf2f(ud.x), wd, s0); s1 = fmaf(bf2f(ud.y), wd, s1);
        s2 = fmaf(bf2f(ud.z), wd, s2); s3 = fmaf(bf2f(ud.w), wd, s3);
    }
    for (; e < e1; e++) {
        int2 ea = adjw[e];
        float wa = __int_as_float(ea.y) * dv;
        ushort4 ua = x4[(size_t)ea.x * 64 + lane];
        p0 = fmaf(bf2f(ua.x), wa, p0); p1 = fmaf(bf2f(ua.y), wa, p1);
        p2 = fmaf(bf2f(ua.z), wa, p2); p3 = fmaf(bf2f(ua.w), wa, p3);
    }
    p0 += q0 + r0 + s0;
    p1 += q1 + r1 + s1;
    p2 += q2 + r2 + s2;
    p3 += q3 + r3 + s3;
    // self loop
    ushort4 uv = x4[(size_t)v * 64 + lane];
    float w2 = dv * dv;
    p0 = fmaf(bf2f(uv.x), w2, p0);
    p1 = fmaf(bf2f(uv.y), w2, p1);
    p2 = fmaf(bf2f(uv.z), w2, p2);
    p3 = fmaf(bf2f(uv.w), w2, p3);
    return make_float4(p0, p1, p2, p3);
}

// standalone gather (layer 1): wave-per-node
__global__ __launch_bounds__(256) void gather1_kernel(
    const ushort* __restrict__ xl, const int* __restrict__ rowptr,
    const int2* __restrict__ adjw, const float* __restrict__ dis,
    ushort* __restrict__ h, int Nn) {
    int wave = threadIdx.x >> 6;
    int lane = threadIdx.x & 63;
    int v = blockIdx.x * 4 + wave;
    if (v >= Nn) return;
    float dv = dis[v];
    float4 s = gather_node((const ushort4*)xl, adjw, rowptr[v], rowptr[v + 1], lane, v, dv);
    ushort4 o;
    o.x = f2bf(s.x); o.y = f2bf(s.y); o.z = f2bf(s.z); o.w = f2bf(s.w);
    ((ushort4*)h)[(size_t)v * 64 + lane] = o;
}

// ---------------- MFMA GEMM: C[M,N] = A[M,K] @ B[N,K]^T (bf16 in/out) ------
// STATS: epilogue emits per-column partial sum/sumsq into psum[col][chunk].
// BN_A:  psum/psumsq are INPUTS (BN1 partials [K][chunks]); bnScale/bnShift
//        carry gamma1/beta1. Prologue reduces them into LDS scale/shift
//        (replaces bn_reduce1), then A-staging applies BN+ReLU in registers.

template <bool STATS, bool BN_A>
__global__ __launch_bounds__(256) void gemm_mfma_kernel(
    const ushort* __restrict__ A, const ushort* __restrict__ B,
    ushort* __restrict__ Cout, float* __restrict__ psum, float* __restrict__ psumsq,
    const float* __restrict__ bnScale, const float* __restrict__ bnShift,
    int chunks, int M, int N, int K) {
    __shared__ ushort As[128 * 32];
    __shared__ ushort Bs[128 * 32];
    __shared__ float scL[512];
    __shared__ float shL[512];
    int tid = threadIdx.x;
    int wave = tid >> 6;
    int lane = tid & 63;
    int quad = lane >> 4;
    int l15 = lane & 15;
    int m0 = blockIdx.y * 128;
    int n0 = blockIdx.x * 128;

    int srow = lane >> 2;
    int skoff = (lane & 3) * 8;

    if (BN_A) {
        // per-block redundant reduce of BN1 partials -> LDS scale/shift
        float invM = 1.0f / (float)M;
        for (int c = tid; c < K; c += 256) {
            float s = 0.f, q = 0.f;
            for (int k = 0; k < chunks; k++) {
                s += psum[(size_t)c * chunks + k];
                q += psumsq[(size_t)c * chunks + k];
            }
            float mean = s * invM;
            float var = q * invM - mean * mean;
            float sc = bnScale[c] * rsqrtf(var + BN_EPS);
            scL[c] = sc;
            shL[c] = bnShift[c] - mean * sc;
        }
        __syncthreads();
    }

    floatx4 acc[4][4];
#pragma unroll
    for (int i = 0; i < 4; i++)
#pragma unroll
        for (int j = 0; j < 4; j++) acc[i][j] = (floatx4){0.f, 0.f, 0.f, 0.f};

    int wm = (wave & 1) * 64;
    int wn = (wave >> 1) * 64;

    for (int k0 = 0; k0 < K; k0 += 32) {
#pragma unroll
        for (int cc = 0; cc < 2; cc++) {
            int c = wave * 2 + cc;
            int brow = n0 + c * 16 + srow;
            const ushort* gb = B + (size_t)brow * K + k0 + skoff;
            GLL(gb, (char*)Bs + c * 1024);
            if (!BN_A) {
                int arow = min(m0 + c * 16 + srow, M - 1);
                const ushort* ga = A + (size_t)arow * K + k0 + skoff;
                GLL(ga, (char*)As + c * 1024);
            }
        }
        if (BN_A) {
            float scv[8], shv[8];
#pragma unroll
            for (int j = 0; j < 8; j++) {
                scv[j] = scL[k0 + skoff + j];
                shv[j] = shL[k0 + skoff + j];
            }
#pragma unroll
            for (int cc = 0; cc < 2; cc++) {
                int c = wave * 2 + cc;
                int arow = min(m0 + c * 16 + srow, M - 1);
                ushort8v araw = *(const ushort8v*)(A + (size_t)arow * K + k0 + skoff);
                ushort8v t;
#pragma unroll
                for (int j = 0; j < 8; j++) {
                    float f = fmaxf(fmaf(bf2f(araw[j]), scv[j], shv[j]), 0.f);
                    t[j] = f2bf(f);
                }
                // tail barrier of previous iter guarantees buffer is free
                *(ushort8v*)((char*)As + c * 1024 + (size_t)lane * 16) = t;
            }
        }
        __syncthreads();

        short8 af[4], bfr[4];
#pragma unroll
        for (int i = 0; i < 4; i++) {
            int r = wm + i * 16 + l15;
            af[i] = *(const short8*)(As + r * 32 + quad * 8);
        }
#pragma unroll
        for (int j = 0; j < 4; j++) {
            int r = wn + j * 16 + l15;
            bfr[j] = *(const short8*)(Bs + r * 32 + quad * 8);
        }
#pragma unroll
        for (int i = 0; i < 4; i++)
#pragma unroll
            for (int j = 0; j < 4; j++)
                acc[i][j] = __builtin_amdgcn_mfma_f32_16x16x32_bf16(af[i], bfr[j], acc[i][j], 0, 0, 0);
        __syncthreads();
    }

#pragma unroll
    for (int i = 0; i < 4; i++) {
#pragma unroll
        for (int r = 0; r < 4; r++) {
            int row = m0 + wm + i * 16 + quad * 4 + r;
            if (row < M) {
                ushort* cp = Cout + (size_t)row * N + n0 + wn + l15;
#pragma unroll
                for (int j = 0; j < 4; j++) cp[j * 16] = f2bf(acc[i][j][r]);
            }
        }
    }

    if (STATS) {
        float s[4] = {0.f, 0.f, 0.f, 0.f};
        float q[4] = {0.f, 0.f, 0.f, 0.f};
#pragma unroll
        for (int i = 0; i < 4; i++) {
#pragma unroll
            for (int r = 0; r < 4; r++) {
                if (m0 + wm + i * 16 + quad * 4 + r < M) {
#pragma unroll
                    for (int j = 0; j < 4; j++) {
                        float v = acc[i][j][r];
                        s[j] += v;
                        q[j] += v * v;
                    }
                }
            }
        }
#pragma unroll
        for (int j = 0; j < 4; j++) {
            s[j] += __shfl_xor(s[j], 16, 64);
            s[j] += __shfl_xor(s[j], 32, 64);
            q[j] += __shfl_xor(q[j], 16, 64);
            q[j] += __shfl_xor(q[j], 32, 64);
        }
        __shared__ float sArr[4][64];
        __shared__ float qArr[4][64];
        if (quad == 0) {
#pragma unroll
            for (int j = 0; j < 4; j++) {
                sArr[wave][j * 16 + l15] = s[j];
                qArr[wave][j * 16 + l15] = q[j];
            }
        }
        __syncthreads();
        if (tid < 128) {
            int half = tid >> 6;
            int cc = tid & 63;
            float ss = sArr[half * 2][cc] + sArr[half * 2 + 1][cc];
            float qq = qArr[half * 2][cc] + qArr[half * 2 + 1][cc];
            int colI = n0 + half * 64 + cc;
            psum[(size_t)colI * chunks + blockIdx.y] = ss;
            psumsq[(size_t)colI * chunks + blockIdx.y] = qq;
        }
    }
}

// ---------------- tail (cooperative): gather2 + BN2 stats + final ----------
// P1: wave-per-node gather, h2 write, per-thread fp32 stats -> per-block
//     partial [block][C] (non-atomic, chunk-owned).
// P2: 256 blocks reduce one channel each -> scale2/shift2.
// P3: out = relu(bn2(h2) + x), grid-stride.
// NO early returns (grid.sync participation).

__global__ __launch_bounds__(256, 4) void tail_coop_kernel(
    const ushort* __restrict__ xl2, const int* __restrict__ rowptr,
    const int2* __restrict__ adjw, const float* __restrict__ dis,
    const float* __restrict__ x, const float* __restrict__ g2,
    const float* __restrict__ b2, ushort* __restrict__ h2,
    float* __restrict__ psumB, float* __restrict__ psumsqB,
    float* __restrict__ scale2, float* __restrict__ shift2,
    float* __restrict__ out, int Nn, int C, int total4) {
    cg::grid_group grid = cg::this_grid();
    int tid = threadIdx.x;
    int wave = tid >> 6;
    int lane = tid & 63;
    const ushort4* x4 = (const ushort4*)xl2;

    // ---- P1: gather + register stats ----
    float ts0 = 0.f, ts1 = 0.f, ts2 = 0.f, ts3 = 0.f;
    float tq0 = 0.f, tq1 = 0.f, tq2 = 0.f, tq3 = 0.f;
    int nwaves = gridDim.x * 4;
    for (int v = blockIdx.x * 4 + wave; v < Nn; v += nwaves) {
        float dv = dis[v];
        float4 s = gather_node(x4, adjw, rowptr[v], rowptr[v + 1], lane, v, dv);
        ushort4 o;
        o.x = f2bf(s.x); o.y = f2bf(s.y); o.z = f2bf(s.z); o.w = f2bf(s.w);
        ((ushort4*)h2)[(size_t)v * 64 + lane] = o;
        ts0 += s.x; ts1 += s.y; ts2 += s.z; ts3 += s.w;
        tq0 += s.x * s.x; tq1 += s.y * s.y; tq2 += s.z * s.z; tq3 += s.w * s.w;
    }
    __shared__ float4 redS[4][64];
    __shared__ float4 redQ[4][64];
    redS[wave][lane] = make_float4(ts0, ts1, ts2, ts3);
    redQ[wave][lane] = make_float4(tq0, tq1, tq2, tq3);
    __syncthreads();
    if (wave == 0) {
        float4 a = redS[0][lane], b = redS[1][lane], c = redS[2][lane], d = redS[3][lane];
        a.x += b.x + c.x + d.x;
        a.y += b.y + c.y + d.y;
        a.z += b.z + c.z + d.z;
        a.w += b.w + c.w + d.w;
        ((float4*)(psumB + (size_t)blockIdx.x * C))[lane] = a;
        float4 e = redQ[0][lane], f = redQ[1][lane], g = redQ[2][lane], h = redQ[3][lane];
        e.x += f.x + g.x + h.x;
        e.y += f.y + g.y + h.y;
        e.z += f.z + g.z + h.z;
        e.w += f.w + g.w + h.w;
        ((float4*)(psumsqB + (size_t)blockIdx.x * C))[lane] = e;
    }
    grid.sync();

    // ---- P2: per-channel reduce -> scale/shift ----
    if (blockIdx.x < (unsigned)C) {
        int c = blockIdx.x;
        float s = 0.f, q = 0.f;
        int nchunk = gridDim.x;
        for (int k = tid; k < nchunk; k += 256) {
            s += psumB[(size_t)k * C + c];
            q += psumsqB[(size_t)k * C + c];
        }
#pragma unroll
        for (int off = 32; off > 0; off >>= 1) {
            s += __shfl_down(s, off, 64);
            q += __shfl_down(q, off, 64);
        }
        __shared__ float w8[8];
        if (lane == 0) { w8[wave] = s; w8[4 + wave] = q; }
        __syncthreads();
        if (tid == 0) {
            s = w8[0] + w8[1] + w8[2] + w8[3];
            q = w8[4] + w8[5] + w8[6] + w8[7];
            float invN = 1.0f / (float)Nn;
            float mean = s * invN;
            float var = q * invN - mean * mean;
            float sc = g2[c] * rsqrtf(var + BN_EPS);
            scale2[c] = sc;
            shift2[c] = b2[c] - mean * sc;
        }
    }
    grid.sync();

    // ---- P3: final epilogue ----
    int C4 = C >> 2;
    for (int idx = blockIdx.x * 256 + tid; idx < total4; idx += gridDim.x * 256) {
        int c4 = (idx & (C4 - 1)) * 4;
        ushort4 u = ((const ushort4*)h2)[idx];
        float4 xv = ((const float4*)x)[idx];
        float4 o;
        o.x = fmaxf(fmaf(bf2f(u.x), scale2[c4 + 0], shift2[c4 + 0]) + xv.x, 0.f);
        o.y = fmaxf(fmaf(bf2f(u.y), scale2[c4 + 1], shift2[c4 + 1]) + xv.y, 0.f);
        o.z = fmaxf(fmaf(bf2f(u.z), scale2[c4 + 2], shift2[c4 + 2]) + xv.z, 0.f);
        o.w = fmaxf(fmaf(bf2f(u.w), scale2[c4 + 3], shift2[c4 + 3]) + xv.w, 0.f);
        ((float4*)out)[idx] = o;
    }
}

// ---------------- launch ----------------

extern "C" void kernel_launch(void* const* d_in, const int* in_sizes, int n_in,
                              void* d_out, int out_size, void* d_ws, size_t ws_size,
                              hipStream_t stream) {
    const float* x  = (const float*)d_in[0];
    const int*   es = (const int*)d_in[1];
    const float* W1 = (const float*)d_in[2];
    const float* g1 = (const float*)d_in[3];
    const float* b1 = (const float*)d_in[4];
    const float* W2 = (const float*)d_in[5];
    const float* g2 = (const float*)d_in[6];
    const float* b2 = (const float*)d_in[7];
    float* out = (float*)d_out;

    const int E  = in_sizes[1] / 2;
    const int IC = in_sizes[3];   // 512
    const int C  = in_sizes[7];   // 256
    const int N  = in_sizes[0] / C;
    const int MTILES = (N + 127) / 128;   // 79
    const int TG = 1024;                  // tail coop grid (4 blocks/CU)

    const int* row = es;
    const int* col = es + E;

    // ---- workspace layout (cnt first: single memset) ----
    char* w = (char*)d_ws;
    size_t off = 0;
    auto alloc = [&](size_t bytes) -> void* {
        void* p = w + off;
        off = (off + bytes + 255) & ~(size_t)255;
        return p;
    };
    int*   cnt     = (int*)alloc((size_t)N * 4);
    float* dis     = (float*)alloc((size_t)N * 4);
    int*   rowptr  = (int*)alloc((size_t)(N + 1) * 4);
    int*   cursor  = (int*)alloc((size_t)N * 4);
    int2*  adjw    = (int2*)alloc((size_t)E * 8);
    float* psum1   = (float*)alloc((size_t)IC * MTILES * 4);
    float* psumsq1 = (float*)alloc((size_t)IC * MTILES * 4);
    float* psumB   = (float*)alloc((size_t)TG * C * 4);
    float* psumsqB = (float*)alloc((size_t)TG * C * 4);
    float* scale2  = (float*)alloc((size_t)C * 4);
    float* shift2  = (float*)alloc((size_t)C * 4);
    ushort* xbf    = (ushort*)alloc((size_t)N * C * 2);
    ushort* W1bf   = (ushort*)alloc((size_t)IC * C * 2);
    ushort* W2bf   = (ushort*)alloc((size_t)IC * C * 2);
    ushort* g1x    = (ushort*)alloc((size_t)N * C * 2);
    ushort* h1raw  = (ushort*)alloc((size_t)N * IC * 2);  // GEMM1 out, bf16 (pre-BN)
    ushort* xl2bf  = (ushort*)alloc((size_t)N * C * 2);
    ushort* h2     = (ushort*)alloc((size_t)N * C * 2);   // gather2 out, bf16

    hipMemsetAsync(cnt, 0, (size_t)N * 4, stream);

    // ---- prep: degree count + bf16 casts ----
    {
        int n4x = N * C / 4, n4w = IC * C / 4;
        int tot = E + n4x + 2 * n4w;
        prep_kernel<<<(tot + 255) / 256, 256, 0, stream>>>(
            col, cnt, x, W1, W2, xbf, W1bf, W2bf, E, n4x, n4w);
    }
    scan_dis_kernel<<<1, 1024, 0, stream>>>(cnt, dis, rowptr, cursor, N);
    scatter_kernel<<<(E + 255) / 256, 256, 0, stream>>>(row, col, dis, cursor, adjw, E);

    // ---- layer 1: g1x = A_norm(x); h1raw = g1x @ W1^T (bf16 + stats1) ----
    gather1_kernel<<<(N + 3) / 4, 256, 0, stream>>>(xbf, rowptr, adjw, dis, g1x, N);
    {
        dim3 grid(IC / 128, MTILES);
        gemm_mfma_kernel<true, false><<<grid, 256, 0, stream>>>(
            g1x, W1bf, h1raw, psum1, psumsq1, nullptr, nullptr, MTILES, N, IC, C);
    }

    // ---- layer 2: GEMM2 prologue reduces BN1 partials (replaces bn_reduce1);
    //      xl2 = relu(bn1(h1raw)) @ W2^T ----
    {
        dim3 grid(C / 128, MTILES);
        gemm_mfma_kernel<false, true><<<grid, 256, 0, stream>>>(
            h1raw, W2bf, xl2bf, psum1, psumsq1, g1, b1, MTILES, N, C, IC);
    }

    // ---- tail: gather2 + BN2 stats + scale/shift + final (one coop kernel) --
    {
        int total4 = (N * C) / 4;
        int Cv = C;
        void* args[] = {(void*)&xl2bf, (void*)&rowptr, (void*)&adjw, (void*)&dis,
                        (void*)&x, (void*)&g2, (void*)&b2, (void*)&h2,
                        (void*)&psumB, (void*)&psumsqB, (void*)&scale2, (void*)&shift2,
                        (void*)&out, (void*)&N, (void*)&Cv, (void*)&total4};
        hipLaunchCooperativeKernel((const void*)tail_coop_kernel,
                                   dim3(TG), dim3(256), args, 0, stream);
    }
}